// Round 1
// baseline (60.849 us; speedup 1.0000x reference)
//
#include <hip/hip_runtime.h>
#include <hip/hip_bf16.h>

#define N 8192
#define D 128
#define JC 8                 // j-chunks (grid parallelism over j)
#define BM 64                // rows per block
#define NRB (N / BM)         // 128 row-blocks
#define JCH (N / JC)         // 1024 columns per chunk

typedef __attribute__((ext_vector_type(8))) short bf16x8;
typedef __attribute__((ext_vector_type(4))) float f32x4;

// ---------------- Stage 0: row-normalize z -> bf16 zn ----------------
__global__ __launch_bounds__(256) void znorm_kernel(const float* __restrict__ z,
                                                    ushort* __restrict__ zn) {
    const int wid  = threadIdx.x >> 6;
    const int lane = threadIdx.x & 63;
    const int row  = blockIdx.x * 4 + wid;       // grid = N/4 blocks
    const float2 v = reinterpret_cast<const float2*>(z + (size_t)row * D)[lane];
    float ss = v.x * v.x + v.y * v.y;
    #pragma unroll
    for (int m = 1; m < 64; m <<= 1) ss += __shfl_xor(ss, m);
    const float inv = 1.0f / fmaxf(sqrtf(ss), 1e-8f);
    __hip_bfloat16 b0 = __float2bfloat16(v.x * inv);
    __hip_bfloat16 b1 = __float2bfloat16(v.y * inv);
    ushort2 o;
    o.x = *reinterpret_cast<ushort*>(&b0);
    o.y = *reinterpret_cast<ushort*>(&b1);
    reinterpret_cast<ushort2*>(zn + (size_t)row * D)[lane] = o;
}

// ---------------- Stage 1: streaming MFMA reductions ----------------
// Per block: rows [rowBase, rowBase+64), j in [chunk*JCH, (chunk+1)*JCH).
// Each wave processes all 64 rows for its own strided 16-wide j slice.
__global__ __launch_bounds__(256) void supcon_main(const ushort* __restrict__ zn,
                                                   const int* __restrict__ y,
                                                   float* __restrict__ pZ,
                                                   float* __restrict__ pS,
                                                   float* __restrict__ pC) {
    const int wid  = threadIdx.x >> 6;
    const int lane = threadIdx.x & 63;
    const int g    = lane >> 4;      // 0..3 lane group
    const int lj   = lane & 15;      // col within tile / row within A-frag
    const int rowBlk = blockIdx.x % NRB;
    const int chunk  = blockIdx.x / NRB;
    const int rowBase = rowBlk * BM;

    // Preload A fragments: 4 M-tiles x 4 K-steps, 8 bf16 each (lane row = lj)
    bf16x8 a[4][4];
    #pragma unroll
    for (int t = 0; t < 4; ++t) {
        const ushort* rp = zn + (size_t)(rowBase + t * 16 + lj) * D;
        #pragma unroll
        for (int s = 0; s < 4; ++s)
            a[t][s] = *reinterpret_cast<const bf16x8*>(rp + s * 32 + g * 8);
    }
    // Labels for the 16 rows this lane's acc elements map to (C layout m89)
    int yi[4][4];
    #pragma unroll
    for (int t = 0; t < 4; ++t)
        #pragma unroll
        for (int r = 0; r < 4; ++r)
            yi[t][r] = y[rowBase + t * 16 + g * 4 + r];

    float Z[4][4], S[4][4], C[4][4];
    #pragma unroll
    for (int t = 0; t < 4; ++t)
        #pragma unroll
        for (int r = 0; r < 4; ++r) { Z[t][r] = 0.f; S[t][r] = 0.f; C[t][r] = 0.f; }

    const f32x4 zero4 = {0.f, 0.f, 0.f, 0.f};
    const int jEnd = chunk * JCH + JCH;
    for (int jt = chunk * JCH + wid * 16; jt < jEnd; jt += 64) {
        const int jg = jt + lj;
        const ushort* jp = zn + (size_t)jg * D;
        bf16x8 b[4];
        #pragma unroll
        for (int s = 0; s < 4; ++s)
            b[s] = *reinterpret_cast<const bf16x8*>(jp + s * 32 + g * 8);
        const int yj = y[jg];

        f32x4 acc[4] = {zero4, zero4, zero4, zero4};
        #pragma unroll
        for (int s = 0; s < 4; ++s)
            #pragma unroll
            for (int t = 0; t < 4; ++t)
                acc[t] = __builtin_amdgcn_mfma_f32_16x16x32_bf16(a[t][s], b[s], acc[t], 0, 0, 0);

        #pragma unroll
        for (int t = 0; t < 4; ++t)
            #pragma unroll
            for (int r = 0; r < 4; ++r) {
                const float dot = acc[t][r];
                const int   ig  = rowBase + t * 16 + g * 4 + r;
                const bool self = (ig == jg);
                const bool pos  = (yj == yi[t][r]) && !self;
                const float e   = __expf(fmaf(dot, 10.0f, -10.0f)); // exp(sim-10)
                Z[t][r] += self ? 0.0f : e;
                S[t][r] += pos ? dot : 0.0f;   // accumulate raw dot; *10 at finalize
                C[t][r] += pos ? 1.0f : 0.0f;
            }
    }

    // Reduce across the 16 lanes of each group (cols of the wave's j slice)
    #pragma unroll
    for (int t = 0; t < 4; ++t)
        #pragma unroll
        for (int r = 0; r < 4; ++r)
            #pragma unroll
            for (int m = 1; m < 16; m <<= 1) {
                Z[t][r] += __shfl_xor(Z[t][r], m);
                S[t][r] += __shfl_xor(S[t][r], m);
                C[t][r] += __shfl_xor(C[t][r], m);
            }

    // Deterministic cross-wave combine via LDS
    __shared__ float red[4][BM][3];
    if (lj == 0) {
        #pragma unroll
        for (int t = 0; t < 4; ++t)
            #pragma unroll
            for (int r = 0; r < 4; ++r) {
                const int rl = t * 16 + g * 4 + r;
                red[wid][rl][0] = Z[t][r];
                red[wid][rl][1] = S[t][r];
                red[wid][rl][2] = C[t][r];
            }
    }
    __syncthreads();
    if (threadIdx.x < BM) {
        const int rl = threadIdx.x;
        float z = 0.f, s = 0.f, c = 0.f;
        #pragma unroll
        for (int w = 0; w < 4; ++w) {
            z += red[w][rl][0];
            s += red[w][rl][1];
            c += red[w][rl][2];
        }
        const int rg = rowBase + rl;
        pZ[chunk * N + rg] = z;
        pS[chunk * N + rg] = s;
        pC[chunk * N + rg] = c;
    }
}

// ---------------- Stage 2: finalize loss ----------------
__global__ __launch_bounds__(256) void supcon_finalize(const float* __restrict__ pZ,
                                                       const float* __restrict__ pS,
                                                       const float* __restrict__ pC,
                                                       float* __restrict__ out) {
    const int i = blockIdx.x * 256 + threadIdx.x;
    float z = 0.f, s = 0.f, c = 0.f;
    #pragma unroll
    for (int k = 0; k < JC; ++k) {
        z += pZ[k * N + i];
        s += pS[k * N + i];
        c += pC[k * N + i];
    }
    const float denom = fmaxf(c, 1.0f);
    const float lse   = 10.0f + logf(z);            // LSE_i = 10 + log Z_i
    out[i] = -(10.0f * s) / denom + (c > 0.0f ? lse : 0.0f);
}

extern "C" void kernel_launch(void* const* d_in, const int* in_sizes, int n_in,
                              void* d_out, int out_size, void* d_ws, size_t ws_size,
                              hipStream_t stream) {
    const float* z = (const float*)d_in[0];
    const int*   y = (const int*)d_in[1];
    float* out = (float*)d_out;

    // ws layout: [0, 2MB) zn bf16; then Z/S/C partials [JC][N] each
    ushort* zn = (ushort*)d_ws;
    float*  pZ = (float*)((char*)d_ws + (size_t)N * D * 2);
    float*  pS = pZ + (size_t)JC * N;
    float*  pC = pS + (size_t)JC * N;

    znorm_kernel<<<N / 4, 256, 0, stream>>>(z, zn);
    supcon_main<<<NRB * JC, 256, 0, stream>>>(zn, y, pZ, pS, pC);
    supcon_finalize<<<N / 256, 256, 0, stream>>>(pZ, pS, pC, out);
}